// Round 9
// baseline (127.366 us; speedup 1.0000x reference)
//
#include <hip/hip_runtime.h>

#define TPB 256
#define R 8           // source points per lane (~40 live VGPRs: below fission threshold)
#define CHUNKS 64     // CH = N/CHUNKS = 256 targets per block
#define CH 256
constexpr int N = 16384;
// SB = N/(TPB*R) = 8 source-blocks/dir; grid = 2*SB*CHUNKS = 1024 blocks = 4/CU

__device__ __forceinline__ float rdlane(float v, int l) {
    return __int_as_float(__builtin_amdgcn_readlane(__float_as_int(v), l));
}

// Pack {x,y,z,|p|^2}; init pmins = 0xFFFFFFFF (uint-max), acc/cnt = 0.
__global__ __launch_bounds__(TPB) void prep_kernel(
        const float* __restrict__ a, const float* __restrict__ b,
        float4* __restrict__ pa, float4* __restrict__ pb,
        unsigned* __restrict__ pmins, float* __restrict__ acc,
        unsigned* __restrict__ cnt) {
    int idx = blockIdx.x * blockDim.x + threadIdx.x;
    if (idx < N) {
        float x = a[3 * idx], y = a[3 * idx + 1], z = a[3 * idx + 2];
        pa[idx] = make_float4(x, y, z, x * x + y * y + z * z);
    } else if (idx < 2 * N) {
        int i = idx - N;
        float x = b[3 * i], y = b[3 * i + 1], z = b[3 * i + 2];
        pb[i] = make_float4(x, y, z, x * x + y * y + z * z);
    }
    if (idx < 2 * N) pmins[idx] = 0xFFFFFFFFu;
    if (idx == 0) { acc[0] = 0.0f; cnt[0] = 0u; }
}

// min_t(|s-t|^2) = |s|^2 + min_t(|t|^2 - 2 s.t)
// Targets: one coalesced float4/lane per 64 targets, broadcast via v_readlane
// (VALU pipe). No LDS, no __syncthreads, no per-target memory op.
__global__ __launch_bounds__(TPB, 4) void minpass_kernel(
        const float4* __restrict__ pa, const float4* __restrict__ pb,
        unsigned* __restrict__ pmins) {
    const int SB = N / (TPB * R);   // 8
    int b = blockIdx.x;
    int dir = b / (SB * CHUNKS);
    int rem = b % (SB * CHUNKS);
    int chunk = rem / SB;
    int sblk = rem % SB;
    const float4* __restrict__ src = dir ? pb : pa;
    const float4* __restrict__ tgt = dir ? pa : pb;

    float ax[R], ay[R], az[R], sw[R], m[R];
    int s0 = sblk * TPB * R + threadIdx.x;  // stride-TPB between r's: coalesced
#pragma unroll
    for (int r = 0; r < R; ++r) {
        float4 s = src[s0 + r * TPB];
        ax[r] = -2.0f * s.x; ay[r] = -2.0f * s.y; az[r] = -2.0f * s.z;
        sw[r] = s.w; m[r] = __builtin_inff();
    }

    int lane = threadIdx.x & 63;
    int base = chunk * CH + lane;
    float4 cur = tgt[base];                 // group-0 targets, 64/wave
#pragma unroll 1
    for (int g = 0; g < CH / 64; ++g) {
        float4 nxt = tgt[base + (((g + 1) & (CH / 64 - 1)) << 6)];  // prefetch (wraps)
#pragma unroll 8
        for (int j = 0; j < 64; j += 2) {
            float px0 = rdlane(cur.x, j),     py0 = rdlane(cur.y, j);
            float pz0 = rdlane(cur.z, j),     pw0 = rdlane(cur.w, j);
            float px1 = rdlane(cur.x, j + 1), py1 = rdlane(cur.y, j + 1);
            float pz1 = rdlane(cur.z, j + 1), pw1 = rdlane(cur.w, j + 1);
#pragma unroll
            for (int r = 0; r < R; ++r) {
                float d0 = fmaf(ax[r], px0, fmaf(ay[r], py0, fmaf(az[r], pz0, pw0)));
                float d1 = fmaf(ax[r], px1, fmaf(ay[r], py1, fmaf(az[r], pz1, pw1)));
                m[r] = fminf(m[r], fminf(d0, d1));  // -> v_min3_f32
            }
        }
        cur = nxt;
    }

    // nonneg floats monotone under unsigned compare -> uint atomicMin
#pragma unroll
    for (int r = 0; r < R; ++r)
        atomicMin(&pmins[dir * N + s0 + r * TPB], __float_as_uint(m[r] + sw[r]));
}

// 32 blocks x 256 threads: each thread sums one uint4; atomicAdd + gated out.
__global__ __launch_bounds__(TPB) void finalize_kernel(
        const uint4* __restrict__ pmins, float* __restrict__ acc,
        unsigned* __restrict__ cnt, float* __restrict__ out, int nblocks) {
    int i = blockIdx.x * TPB + threadIdx.x;  // i-th uint4, total 2N/4
    uint4 v = pmins[i];
    float sum = __uint_as_float(v.x) + __uint_as_float(v.y)
              + __uint_as_float(v.z) + __uint_as_float(v.w);
    for (int off = 32; off > 0; off >>= 1)
        sum += __shfl_down(sum, off, 64);
    __shared__ float wsum[TPB / 64];
    int lane = threadIdx.x & 63, wid = threadIdx.x >> 6;
    if (lane == 0) wsum[wid] = sum;
    __syncthreads();
    if (threadIdx.x == 0) {
        float t = 0.0f;
        for (int w = 0; w < TPB / 64; ++w) t += wsum[w];
        atomicAdd(acc, t);
        __threadfence();
        unsigned old = atomicAdd(cnt, 1u);
        if (old == (unsigned)(nblocks - 1)) {
            float a0 = atomicAdd(acc, 0.0f);  // device-scope coherent read
            out[0] = a0 / (float)(2 * N);
        }
    }
}

extern "C" void kernel_launch(void* const* d_in, const int* in_sizes, int n_in,
                              void* d_out, int out_size, void* d_ws, size_t ws_size,
                              hipStream_t stream) {
    const float* a = (const float*)d_in[0];
    const float* b = (const float*)d_in[1];
    float* out = (float*)d_out;
    char* ws = (char*)d_ws;
    float* acc = (float*)ws;                 // 1 float
    unsigned* cnt = (unsigned*)(ws + 8);     // 1 uint
    float4* pa = (float4*)(ws + 256);        // N float4
    float4* pb = pa + N;                     // N float4
    unsigned* pmins = (unsigned*)(ws + 256 + 2 * (size_t)N * sizeof(float4));

    prep_kernel<<<(2 * N + TPB - 1) / TPB, TPB, 0, stream>>>(
        a, b, pa, pb, pmins, acc, cnt);
    int SB = N / (TPB * R);
    minpass_kernel<<<2 * SB * CHUNKS, TPB, 0, stream>>>(pa, pb, pmins);
    int fblocks = (2 * N / 4) / TPB;  // 32
    finalize_kernel<<<fblocks, TPB, 0, stream>>>(
        (const uint4*)pmins, acc, cnt, out, fblocks);
}

// Round 10
// 102.588 us; speedup vs baseline: 1.2415x; 1.2415x over previous
//
#include <hip/hip_runtime.h>

#define TPB 256
#define R 8           // source points per lane
#define CHUNKS 64     // CH = N/CHUNKS = 256 targets per block
#define CH 256
constexpr int N = 16384;
// SB = N/(TPB*R) = 8 source-blocks/dir; grid = 2*SB*CHUNKS = 1024 blocks = 4/CU

typedef __attribute__((ext_vector_type(2))) float v2;
typedef __attribute__((ext_vector_type(4))) float v4;

__device__ __forceinline__ v2 vfma(v2 a, v2 b, v2 c) {
    return __builtin_elementwise_fma(a, b, c);   // -> v_pk_fma_f32
}
__device__ __forceinline__ v2 vmin(v2 a, v2 b) {
    return __builtin_elementwise_min(a, b);      // -> 2x v_min_f32 / v_min3
}

// Pack {x,y,z,|p|^2}; init pmins = 0xFFFFFFFF (uint-max), acc/cnt = 0.
__global__ __launch_bounds__(TPB) void prep_kernel(
        const float* __restrict__ a, const float* __restrict__ b,
        float4* __restrict__ pa, float4* __restrict__ pb,
        unsigned* __restrict__ pmins, float* __restrict__ acc,
        unsigned* __restrict__ cnt) {
    int idx = blockIdx.x * blockDim.x + threadIdx.x;
    if (idx < N) {
        float x = a[3 * idx], y = a[3 * idx + 1], z = a[3 * idx + 2];
        pa[idx] = make_float4(x, y, z, x * x + y * y + z * z);
    } else if (idx < 2 * N) {
        int i = idx - N;
        float x = b[3 * i], y = b[3 * i + 1], z = b[3 * i + 2];
        pb[i] = make_float4(x, y, z, x * x + y * y + z * z);
    }
    if (idx < 2 * N) pmins[idx] = 0xFFFFFFFFu;
    if (idx == 0) { acc[0] = 0.0f; cnt[0] = 0u; }
}

// min_t(|s-t|^2) = |s|^2 + min_t(|t|^2 - 2 s.t)
// Tile stored target-PAIRED: pair q = {x0,x1,y0,y1} {z0,z1,w0,w1} so each
// ds_read_b128 lands in a pk-ready register pair; inner math is v_pk_fma_f32.
__global__ __launch_bounds__(TPB, 4) void minpass_kernel(
        const float4* __restrict__ pa, const float4* __restrict__ pb,
        unsigned* __restrict__ pmins) {
    const int SB = N / (TPB * R);   // 8
    int blk = blockIdx.x;
    int dir = blk / (SB * CHUNKS);
    int rem = blk % (SB * CHUNKS);
    int chunk = rem / SB;
    int sblk = rem % SB;
    const float4* __restrict__ src = dir ? pb : pa;
    const float4* __restrict__ tgt = dir ? pa : pb;

    __shared__ v4 tile[CH];  // 2 v4 per pair, CH/2 pairs, 4 KB
    int base = chunk * CH;
    for (int q = threadIdx.x; q < CH / 2; q += TPB) {
        float4 p0 = tgt[base + 2 * q], p1 = tgt[base + 2 * q + 1];
        tile[2 * q]     = (v4){p0.x, p1.x, p0.y, p1.y};
        tile[2 * q + 1] = (v4){p0.z, p1.z, p0.w, p1.w};
    }

    v2 ax[R], ay[R], az[R], m2[R];
    float sw[R];
    int s0 = sblk * TPB * R + threadIdx.x;  // stride-TPB between r's: coalesced
#pragma unroll
    for (int r = 0; r < R; ++r) {
        float4 s = src[s0 + r * TPB];
        ax[r] = (v2){-2.0f * s.x, -2.0f * s.x};
        ay[r] = (v2){-2.0f * s.y, -2.0f * s.y};
        az[r] = (v2){-2.0f * s.z, -2.0f * s.z};
        sw[r] = s.w;
        m2[r] = (v2){__builtin_inff(), __builtin_inff()};
    }
    __syncthreads();

    // 2 pairs (4 targets) per body; loads up front so later reads overlap
    // earlier pk_fma chains. distribute(disable): keep r fully blocked.
#pragma clang loop unroll_count(2) distribute(disable)
    for (int q = 0; q < CH / 2; q += 2) {
        v4 A0 = tile[2 * q],     B0 = tile[2 * q + 1];
        v4 A1 = tile[2 * q + 2], B1 = tile[2 * q + 3];
        v2 x01 = __builtin_shufflevector(A0, A0, 0, 1);
        v2 y01 = __builtin_shufflevector(A0, A0, 2, 3);
        v2 z01 = __builtin_shufflevector(B0, B0, 0, 1);
        v2 w01 = __builtin_shufflevector(B0, B0, 2, 3);
        v2 x23 = __builtin_shufflevector(A1, A1, 0, 1);
        v2 y23 = __builtin_shufflevector(A1, A1, 2, 3);
        v2 z23 = __builtin_shufflevector(B1, B1, 0, 1);
        v2 w23 = __builtin_shufflevector(B1, B1, 2, 3);
#pragma unroll
        for (int r = 0; r < R; ++r) {
            v2 dA = vfma(ax[r], x01, vfma(ay[r], y01, vfma(az[r], z01, w01)));
            v2 dB = vfma(ax[r], x23, vfma(ay[r], y23, vfma(az[r], z23, w23)));
            m2[r] = vmin(m2[r], vmin(dA, dB));  // -> 2x v_min3_f32
        }
    }

    // nonneg floats monotone under unsigned compare -> uint atomicMin
#pragma unroll
    for (int r = 0; r < R; ++r) {
        float mm = fminf(m2[r].x, m2[r].y) + sw[r];
        atomicMin(&pmins[dir * N + s0 + r * TPB], __float_as_uint(mm));
    }
}

// 32 blocks x 256 threads: each thread sums one uint4; atomicAdd + gated out.
__global__ __launch_bounds__(TPB) void finalize_kernel(
        const uint4* __restrict__ pmins, float* __restrict__ acc,
        unsigned* __restrict__ cnt, float* __restrict__ out, int nblocks) {
    int i = blockIdx.x * TPB + threadIdx.x;  // i-th uint4, total 2N/4
    uint4 v = pmins[i];
    float sum = __uint_as_float(v.x) + __uint_as_float(v.y)
              + __uint_as_float(v.z) + __uint_as_float(v.w);
    for (int off = 32; off > 0; off >>= 1)
        sum += __shfl_down(sum, off, 64);
    __shared__ float wsum[TPB / 64];
    int lane = threadIdx.x & 63, wid = threadIdx.x >> 6;
    if (lane == 0) wsum[wid] = sum;
    __syncthreads();
    if (threadIdx.x == 0) {
        float t = 0.0f;
        for (int w = 0; w < TPB / 64; ++w) t += wsum[w];
        atomicAdd(acc, t);
        __threadfence();
        unsigned old = atomicAdd(cnt, 1u);
        if (old == (unsigned)(nblocks - 1)) {
            float a0 = atomicAdd(acc, 0.0f);  // device-scope coherent read
            out[0] = a0 / (float)(2 * N);
        }
    }
}

extern "C" void kernel_launch(void* const* d_in, const int* in_sizes, int n_in,
                              void* d_out, int out_size, void* d_ws, size_t ws_size,
                              hipStream_t stream) {
    const float* a = (const float*)d_in[0];
    const float* b = (const float*)d_in[1];
    float* out = (float*)d_out;
    char* ws = (char*)d_ws;
    float* acc = (float*)ws;                 // 1 float
    unsigned* cnt = (unsigned*)(ws + 8);     // 1 uint
    float4* pa = (float4*)(ws + 256);        // N float4
    float4* pb = pa + N;                     // N float4
    unsigned* pmins = (unsigned*)(ws + 256 + 2 * (size_t)N * sizeof(float4));

    prep_kernel<<<(2 * N + TPB - 1) / TPB, TPB, 0, stream>>>(
        a, b, pa, pb, pmins, acc, cnt);
    int SB = N / (TPB * R);
    minpass_kernel<<<2 * SB * CHUNKS, TPB, 0, stream>>>(pa, pb, pmins);
    int fblocks = (2 * N / 4) / TPB;  // 32
    finalize_kernel<<<fblocks, TPB, 0, stream>>>(
        (const uint4*)pmins, acc, cnt, out, fblocks);
}